// Round 1
// 113.553 us; speedup vs baseline: 1.0016x; 1.0016x over previous
//
#include <hip/hip_runtime.h>
#include <math.h>

#define MU_MAXC 32
#define MV_MAXC 32
#define OUT_UC  64
#define OUT_VC  64
#define DEG     3
#define NKNOT   (MU_MAXC + DEG + 1)   // 36
#define EPSV    1e-5f
#define TROW    33   // float4 quads per tmp row (32 data + 1 pad)
#define UH      32   // u-rows per block (half a sample)

__global__ void zero_ws_kernel(double* acc, int* bad) {
    acc[0] = 0.0; acc[1] = 0.0; acc[2] = 0.0; bad[0] = 0;
}

// Clamped open-uniform knot value (padded k >= L-1-DEG clamps to 1.0).
__device__ __forceinline__ float kv_at(int k, int L) {
    return (k <= DEG) ? 0.f : ((k >= L - 1 - DEG) ? 1.f : (float)k / (float)(L - 1));
}

// One block per HALF sample (u-rows [h*32, h*32+32)). 2048 blocks -> 2 resident
// rounds on 256 CUs (VGPR-capped 4 blk/CU), so round-2 Phase-A HBM streaming
// overlaps round-1 C2/D LDS+VALU phases. The 1024-block version was a single
// resident round: HBM, LDS and VALU phases serialized globally (~27us vs
// ~13us HBM floor). LDS/block ~19 KB (was 36.7).
// Other deltas vs previous version:
//  - invSumBu folded into s_Bu4 (removes 3 v_mul/point in D + an LDS array)
//  - mu/mv computed by all threads from ballot partials (one fewer barrier)
//  - xyz prefetched: k=0 issued before the pre-D barrier (hides under C2
//    tail + barrier drain), k=1 issued during k=0 compute
//  - XCD pairing swizzle keeps a sample's two halves on one XCD so C2's
//    ctrl re-reads stay L2-hot (perf heuristic only, correctness-neutral)
template <int MODE>
__launch_bounds__(256)
__global__ void nurbs_loss_kernel(const float* __restrict__ ctrl_pred,
                                  const float* __restrict__ ctrl_gt,
                                  const float* __restrict__ mask,
                                  const float* __restrict__ xyz,
                                  double* __restrict__ pd, int Bcnt,
                                  int* __restrict__ badp)
{
    const int g  = blockIdx.x;
    const int NB = gridDim.x;
    int b, h;
    if ((NB & 15) == 0) {
        // dispatch heuristic: xcd = blockIdx % 8; put both halves of a sample
        // on the same xcd (slot pair 2m,2m+1 of the same xcd).
        const int slot = g >> 3, xcd = g & 7;
        b = (slot >> 1) * 8 + xcd;
        h = slot & 1;
    } else { b = g >> 1; h = g & 1; }
    const int tid = threadIdx.x;

    __shared__ __align__(16) float s_tmp[UH * TROW * 4];  // 16.9 KB padded quads
    __shared__ __align__(16) float s_Bv4[OUT_VC * 4];     // [v][r], /sumBv folded
    __shared__ float s_Bu4[4 * UH];                       // SoA [r][u], /sumBu folded
    __shared__ int   s_uoff[UH];
    __shared__ int   s_voff[OUT_VC];
    __shared__ int   s_bad;
    __shared__ float s_mred[4], s_dred[4], s_sred[4];
    __shared__ int   s_rowcnt[4];
    __shared__ unsigned int s_colmask[4];

    if (tid == 0) s_bad = 0;

    // ---- Phase A: mask ballots (full mask, both halves -> identical mu/mv)
    //      + masked ctrl MSE on this block's half of the cells. ----
    float lsum_mask = 0.f, lsum_diff = 0.f;
    unsigned long long bx, by, bz, bw;
    {
        const float4 mm = ((const float4*)(mask + (size_t)b * 1024))[tid];
        bx = __ballot(mm.x > 0.f);
        by = __ballot(mm.y > 0.f);
        bz = __ballot(mm.z > 0.f);
        bw = __ballot(mm.w > 0.f);
        if (h == 0) lsum_mask = mm.x + mm.y + mm.z + mm.w;  // count mask once
    }
    if (tid < 128) {
        // cells h*512 + 4*tid .. +3 ; their mask quad is L1-hot (just streamed)
        const float4 mm2 = ((const float4*)(mask + (size_t)b * 1024))[h * 128 + tid];
        const float4* p4 = (const float4*)(ctrl_pred + (size_t)b * 3072 + (size_t)h * 1536);
        const float4* g4 = (const float4*)(ctrl_gt   + (size_t)b * 3072 + (size_t)h * 1536);
        const float4 pa = p4[3 * tid + 0], pb = p4[3 * tid + 1], pc = p4[3 * tid + 2];
        const float4 ga = g4[3 * tid + 0], gb = g4[3 * tid + 1], gc = g4[3 * tid + 2];
        const float a0 = pa.x - ga.x, a1 = pa.y - ga.y, a2 = pa.z - ga.z;
        const float b0 = pa.w - ga.w, b1 = pb.x - gb.x, b2 = pb.y - gb.y;
        const float c0 = pb.z - gb.z, c1 = pb.w - gb.w, c2 = pc.x - gc.x;
        const float e0 = pc.y - gc.y, e1 = pc.z - gc.z, e2 = pc.w - gc.w;
        lsum_diff = mm2.x * (a0 * a0 + a1 * a1 + a2 * a2)
                  + mm2.y * (b0 * b0 + b1 * b1 + b2 * b2)
                  + mm2.z * (c0 * c0 + c1 * c1 + c2 * c2)
                  + mm2.w * (e0 * e0 + e1 * e1 + e2 * e2);
    }
    int rowcnt;
    {
        unsigned long long anyb = bx | by | bz | bw;
        unsigned long long t = anyb | (anyb >> 4); t |= t >> 2; t |= t >> 1;
        rowcnt = __popcll(t & 0x0101010101010101ULL);
    }
    bool colany = false;
    {
        const int j = tid & 63;
        if (j < 32) {
            const int comp = j & 3;
            const unsigned long long sel = (comp == 0) ? bx : (comp == 1) ? by
                                          : (comp == 2) ? bz : bw;
            colany = (sel & (0x0101010101010101ULL << (j >> 2))) != 0ULL;
        }
    }
    const unsigned long long cmask = __ballot(colany);   // low 32 bits valid
    #pragma unroll
    for (int off = 32; off > 0; off >>= 1) {
        lsum_mask += __shfl_down(lsum_mask, off);
        lsum_diff += __shfl_down(lsum_diff, off);
    }
    if ((tid & 63) == 0) {
        const int w = tid >> 6;
        s_mred[w] = lsum_mask; s_dred[w] = lsum_diff;
        s_rowcnt[w] = rowcnt;  s_colmask[w] = (unsigned int)cmask;
    }
    __syncthreads();                                     // sync 1

    // every thread derives mu/mv locally (no tid0 step, no second barrier)
    const int cu_ = s_rowcnt[0] + s_rowcnt[1] + s_rowcnt[2] + s_rowcnt[3];
    const int cv_ = __popc(s_colmask[0] | s_colmask[1] | s_colmask[2] | s_colmask[3]);
    const int mu = cu_ > (DEG + 1) ? cu_ : (DEG + 1);
    const int mv = cv_ > (DEG + 1) ? cv_ : (DEG + 1);

    // ---- Phase C: span-based Cox-de Boor, knots on-the-fly.
    //      Bu: threads 0..31 (this half's 32 u-samples); Bv: threads 64..127. ----
    if (tid < 32 || (tid >= 64 && tid < 128)) {
        const bool isU = tid < 32;
        const int t = isU ? tid : (tid - 64);
        const int gidx = isU ? (h * UH + t) : t;         // global sample index 0..63
        const int L = (isU ? mu : mv) + DEG + 1;
        const float step = (1.f - 2.f * EPSV) / 63.f;
        const float uu = (gidx == 63) ? (1.f - EPSV) : (EPSV + step * (float)gidx);

        int span = DEG;
        #pragma unroll
        for (int k = DEG + 1; k < NKNOT - 1; k++)
            if (kv_at(k, L) <= uu) span = k;

        float left[DEG + 1], right[DEG + 1];
        #pragma unroll
        for (int j = 1; j <= DEG; j++) {
            left[j]  = uu - kv_at(span + 1 - j, L);
            right[j] = kv_at(span + j, L) - uu;
        }
        float N4[DEG + 1];
        N4[0] = 1.f;
        #pragma unroll
        for (int j = 1; j <= DEG; j++) {
            float saved = 0.f;
            #pragma unroll
            for (int r = 0; r < j; r++) {
                const float temp = N4[r] / (right[r + 1] + left[j - r]);
                N4[r] = saved + right[r + 1] * temp;
                saved = left[j - r] * temp;
            }
            N4[j] = saved;
        }
        const float invs = 1.0f / (N4[0] + N4[1] + N4[2] + N4[3]);
        const int off = span - DEG;                      // in [0, 28]
        if (isU) {
            #pragma unroll
            for (int r = 0; r < 4; r++) s_Bu4[r * UH + t] = N4[r] * invs;
            s_uoff[t] = off;
        } else {
            ((float4*)s_Bv4)[t] = make_float4(N4[0] * invs, N4[1] * invs,
                                              N4[2] * invs, N4[3] * invs);
            s_voff[t] = off;
        }
    }
    __syncthreads();                                     // sync 2

    // ---- Phase C2: 256 tasks (u-local, j-quad m<8), 1 per thread.
    //      12 float4 ctrl reads (L2-hot on this XCD), 48 MACs, 4 b128 writes. ----
    {
        const float4* ctrl4 = (const float4*)(ctrl_pred + (size_t)b * 3072);
        const int u = tid >> 3;                          // 0..31 local
        const int m = tid & 7;
        const int off = s_uoff[u];
        const float w0 = s_Bu4[0 * UH + u];
        const float w1 = s_Bu4[1 * UH + u];
        const float w2 = s_Bu4[2 * UH + u];
        const float w3 = s_Bu4[3 * UH + u];
        float f[12];
        #pragma unroll
        for (int e = 0; e < 3; e++) {
            const float4 c0 = ctrl4[(off + 0) * 24 + m * 3 + e];
            const float4 c1 = ctrl4[(off + 1) * 24 + m * 3 + e];
            const float4 c2 = ctrl4[(off + 2) * 24 + m * 3 + e];
            const float4 c3 = ctrl4[(off + 3) * 24 + m * 3 + e];
            f[e * 4 + 0] = w0 * c0.x + w1 * c1.x + w2 * c2.x + w3 * c3.x;
            f[e * 4 + 1] = w0 * c0.y + w1 * c1.y + w2 * c2.y + w3 * c3.y;
            f[e * 4 + 2] = w0 * c0.z + w1 * c1.z + w2 * c2.z + w3 * c3.z;
            f[e * 4 + 3] = w0 * c0.w + w1 * c1.w + w2 * c2.w + w3 * c3.w;
        }
        float4* dst = ((float4*)s_tmp) + (u * TROW + m * 4);
        dst[0] = make_float4(f[0], f[1],  f[2],  0.f);
        dst[1] = make_float4(f[3], f[4],  f[5],  0.f);
        dst[2] = make_float4(f[6], f[7],  f[8],  0.f);
        dst[3] = make_float4(f[9], f[10], f[11], 0.f);
    }

    // Pre-read Bv weights/offsets (valid since sync 2) and ISSUE k=0 xyz loads
    // now: their HBM latency hides under other waves' C2 + the barrier drain.
    const int vg = (tid & 15) * 4;
    const int ug = tid >> 4;                             // 0..15
    const float4 wva[4] = { ((const float4*)s_Bv4)[vg + 0],
                            ((const float4*)s_Bv4)[vg + 1],
                            ((const float4*)s_Bv4)[vg + 2],
                            ((const float4*)s_Bv4)[vg + 3] };
    const int voa[4] = { s_voff[vg + 0], s_voff[vg + 1],
                         s_voff[vg + 2], s_voff[vg + 3] };
    const float* xyzb = xyz + ((size_t)b * 4096 + (size_t)h * 2048) * 3;
    const float4* xA = (const float4*)(xyzb + ((size_t)ug * 64 + vg) * 3);
    float4 x0 = xA[0], x1 = xA[1], x2 = xA[2];
    __syncthreads();                                     // sync 3

    // ---- Phase D: 8 points/thread (2 u x 4 consecutive v), k=1 xyz prefetched
    //      during k=0 compute. Per point: 4 ds_read_b128 + 18 VALU (inv folded). ----
    float lsum_surf = 0.f;
    const float4* xB = (const float4*)(xyzb + ((size_t)(ug + 16) * 64 + vg) * 3);
    float4 y0 = xB[0], y1 = xB[1], y2 = xB[2];           // prefetch k=1

    #define POINT4(TROWP, XA, XB, XC)                                        \
    do {                                                                     \
        const float px[4] = {(XA).x, (XA).w, (XB).z, (XC).y};                \
        const float py[4] = {(XA).y, (XB).x, (XB).w, (XC).z};                \
        const float pz[4] = {(XA).z, (XB).y, (XC).x, (XC).w};                \
        _Pragma("unroll")                                                    \
        for (int c = 0; c < 4; c++) {                                        \
            const float4 t0 = (TROWP)[voa[c] + 0];                           \
            const float4 t1 = (TROWP)[voa[c] + 1];                           \
            const float4 t2 = (TROWP)[voa[c] + 2];                           \
            const float4 t3 = (TROWP)[voa[c] + 3];                           \
            const float4 w = wva[c];                                         \
            const float n0 = w.x * t0.x + w.y * t1.x + w.z * t2.x + w.w * t3.x; \
            const float n1 = w.x * t0.y + w.y * t1.y + w.z * t2.y + w.w * t3.y; \
            const float n2 = w.x * t0.z + w.y * t1.z + w.z * t2.z + w.w * t3.z; \
            const float d0 = n0 - px[c];                                     \
            const float d1 = n1 - py[c];                                     \
            const float d2 = n2 - pz[c];                                     \
            lsum_surf += d0 * d0 + d1 * d1 + d2 * d2;                        \
        }                                                                    \
    } while (0)

    POINT4(((const float4*)s_tmp) + ug * TROW,        x0, x1, x2);
    POINT4(((const float4*)s_tmp) + (ug + 16) * TROW, y0, y1, y2);
    #undef POINT4

    // hoisted non-finite check: any non-finite surf value makes the partial
    // +Inf/NaN (squares never cancel back to finite)
    const int bad = !isfinite(lsum_surf);
    #pragma unroll
    for (int off = 32; off > 0; off >>= 1)
        lsum_surf += __shfl_down(lsum_surf, off);
    if ((tid & 63) == 0) s_sred[tid >> 6] = lsum_surf;
    if (bad) atomicOr(&s_bad, 1);
    __syncthreads();                                     // sync 4

    if (tid == 0) {
        const double surf = (double)s_sred[0] + s_sred[1] + s_sred[2] + s_sred[3];
        const double dsum = (double)s_dred[0] + s_dred[1] + s_dred[2] + s_dred[3];
        const double msum = (double)s_mred[0] + s_mred[1] + s_mred[2] + s_mred[3];
        if (MODE == 0) {
            pd[g]          = dsum;
            pd[NB + g]     = msum;
            pd[2 * NB + g] = surf;
            badp[g]        = s_bad;
        } else {
            atomicAdd(&pd[0], dsum);
            atomicAdd(&pd[1], msum);
            atomicAdd(&pd[2], surf);
            if (s_bad) atomicOr(badp, 1);
        }
    }
}

__global__ void finalize_partials_kernel(const double* __restrict__ pd,
                                         const int* __restrict__ badp,
                                         float* __restrict__ out, int Bcnt, int NB)
{
    __shared__ double sd0[4], sd1[4], sd2[4];
    __shared__ int sb[4];
    const int tid = threadIdx.x;
    double a0 = 0.0, a1 = 0.0, a2 = 0.0; int bad = 0;
    for (int i = tid; i < NB; i += 256) {
        a0 += pd[i]; a1 += pd[NB + i]; a2 += pd[2 * NB + i];
        bad |= badp[i];
    }
    #pragma unroll
    for (int off = 32; off > 0; off >>= 1) {
        a0 += __shfl_down(a0, off);
        a1 += __shfl_down(a1, off);
        a2 += __shfl_down(a2, off);
        bad |= __shfl_down(bad, off);
    }
    if ((tid & 63) == 0) { const int w = tid >> 6; sd0[w] = a0; sd1[w] = a1; sd2[w] = a2; sb[w] = bad; }
    __syncthreads();
    if (tid == 0) {
        double d0 = 0, d1 = 0, d2 = 0; int bb = 0;
        #pragma unroll
        for (int i = 0; i < 4; i++) { d0 += sd0[i]; d1 += sd1[i]; d2 += sd2[i]; bb |= sb[i]; }
        const double denc = d1 * 3.0;
        const double lc = d0 / (denc > 1.0 ? denc : 1.0);
        const double ls = d2 / ((double)Bcnt * OUT_UC * OUT_VC * 3.0);
        out[0] = (float)(lc + ls);            // total (pre-nan-guard, per ref)
        out[1] = (float)lc;                   // loss_ctrl
        out[2] = bb ? 1.0e6f : (float)ls;     // surf_mse with nan/inf guard
    }
}

__global__ void finalize_atomic_kernel(const double* __restrict__ acc,
                                       const int* __restrict__ bad,
                                       float* __restrict__ out, int Bcnt)
{
    const double denc = acc[1] * 3.0;
    const double lc = acc[0] / (denc > 1.0 ? denc : 1.0);
    const double ls = acc[2] / ((double)Bcnt * OUT_UC * OUT_VC * 3.0);
    out[0] = (float)(lc + ls);
    out[1] = (float)lc;
    out[2] = bad[0] ? 1.0e6f : (float)ls;
}

extern "C" void kernel_launch(void* const* d_in, const int* in_sizes, int n_in,
                              void* d_out, int out_size, void* d_ws, size_t ws_size,
                              hipStream_t stream)
{
    const float* pred = (const float*)d_in[0];
    const float* gt   = (const float*)d_in[1];
    const float* mask = (const float*)d_in[2];
    const float* xyz  = (const float*)d_in[3];
    const int Bcnt = in_sizes[2] / (MU_MAXC * MV_MAXC);   // 1024 samples
    const int NB = 2 * Bcnt;                              // 2 half-sample blocks each

    double* pd = (double*)d_ws;
    float* out = (float*)d_out;

    const size_t need = (size_t)3 * NB * sizeof(double) + (size_t)NB * sizeof(int);
    if (ws_size >= need) {
        int* badp = (int*)(pd + 3 * NB);
        hipLaunchKernelGGL((nurbs_loss_kernel<0>), dim3(NB), dim3(256), 0, stream,
                           pred, gt, mask, xyz, pd, Bcnt, badp);
        hipLaunchKernelGGL(finalize_partials_kernel, dim3(1), dim3(256), 0, stream,
                           pd, badp, out, Bcnt, NB);
    } else {
        int* badp = (int*)(pd + 3);
        hipLaunchKernelGGL(zero_ws_kernel, dim3(1), dim3(1), 0, stream, pd, badp);
        hipLaunchKernelGGL((nurbs_loss_kernel<1>), dim3(NB), dim3(256), 0, stream,
                           pred, gt, mask, xyz, pd, Bcnt, badp);
        hipLaunchKernelGGL(finalize_atomic_kernel, dim3(1), dim3(1), 0, stream,
                           pd, badp, out, Bcnt);
    }
}